// Round 9
// baseline (10821.862 us; speedup 1.0000x reference)
//
#include <hip/hip_runtime.h>

typedef unsigned short ushort_t;
typedef unsigned int uint_t;
typedef unsigned long long ull_t;
typedef __attribute__((ext_vector_type(8))) short short8;
typedef __attribute__((ext_vector_type(4))) float f32x4;

// ---------------- workspace layout (bytes) ----------------
constexpr size_t OFF_WSFT  = 0;                          // bf16 [512][512] (n,k): W_sf[k][n], k<512
constexpr size_t OFF_WAFT  = OFF_WSFT  + 512*512*2;      // bf16 [512][512]
constexpr size_t OFF_WO1AT = OFF_WAFT  + 512*512*2;      // bf16 [512][512]  W_o1 rows 0..511
constexpr size_t OFF_WO1BT = OFF_WO1AT + 512*512*2;      // bf16 [512][512]  W_o1 rows 512..1023
constexpr size_t OFF_WAST  = OFF_WO1BT + 512*512*2;      // bf16 [512][512]  W_as top
constexpr size_t OFF_WSST  = OFF_WAST  + 512*512*2;      // bf16 [512][512]  W_ss top
constexpr size_t OFF_GAPS  = OFF_WSST  + 512*512*2;      // f32 [200][512]  te@Wsf_bot + b_sf
constexpr size_t OFF_CAFV  = OFF_GAPS  + 200*512*4;      // f32 [512]       te1@Waf_bot + b_af
constexpr size_t OFF_XA    = OFF_CAFV  + 512*4;          // f32 [600][512]  X@Was_bot + b_as
constexpr size_t OFF_XS    = OFF_XA    + 600*512*4;      // f32 [600][512]  X@Wss_bot + b_ss
constexpr size_t OFF_PROJ  = OFF_XS    + 600*512*4;      // f32 [300][512]  se@Wo1c + b_o1
constexpr size_t OFF_LAG   = OFF_PROJ  + 300*512*4;      // bf16 [512][512] gated last_all
constexpr size_t OFF_LSG   = OFF_LAG   + 512*512*2;      // bf16 [512][512] gated last_sk
constexpr size_t OFF_ASG   = OFF_LSG   + 512*512*2;      // bf16 [512][512] all_state
constexpr size_t OFF_ISKR  = OFF_ASG   + 512*512*2;      // i32 [199][512] gather row
constexpr size_t OFF_IGAP  = OFF_ISKR  + 199*512*4;      // i32 [199][512] gap
constexpr size_t OFF_IXR   = OFF_IGAP  + 199*512*4;      // i32 [199][512] X row
constexpr size_t OFF_ISK   = OFF_IXR   + 199*512*4;      // i32 [199][512] skill
constexpr size_t OFF_BAR   = OFF_ISK   + 199*512*4;      // i32 [16][32] barrier counters
constexpr size_t OFF_SKB   = OFF_BAR   + 16*32*4;        // bf16 [512][199][512] skill_buf
constexpr size_t WS_NEED   = OFF_SKB   + (size_t)512*199*512*2;

__device__ __forceinline__ ushort_t f2bf(float f) {
  union { float f; uint_t u; } v; v.f = f;
  uint_t u = v.u;
  return (ushort_t)((u + 0x7FFFu + ((u >> 16) & 1u)) >> 16);
}
__device__ __forceinline__ float bf2f(ushort_t h) {
  union { uint_t u; float f; } v; v.u = ((uint_t)h) << 16;
  return v.f;
}
__device__ __forceinline__ ull_t coh_ld8(const void* p) {
  return __hip_atomic_load((const ull_t*)p, __ATOMIC_RELAXED, __HIP_MEMORY_SCOPE_AGENT);
}
__device__ __forceinline__ void coh_st4(void* p, uint_t v) {
  __hip_atomic_store((uint_t*)p, v, __ATOMIC_RELAXED, __HIP_MEMORY_SCOPE_AGENT);
}

// ---------------- prologue: transposes + state init ----------------
__global__ void rekt_prep(const float* __restrict__ ls_state, const float* __restrict__ skill_state0,
                          const float* __restrict__ W_sf, const float* __restrict__ W_af,
                          const float* __restrict__ W_ss, const float* __restrict__ W_as,
                          const float* __restrict__ W_o1,
                          float* __restrict__ d_out, char* __restrict__ ws) {
  ushort_t* WSFT  = (ushort_t*)(ws + OFF_WSFT);
  ushort_t* WAFT  = (ushort_t*)(ws + OFF_WAFT);
  ushort_t* WO1AT = (ushort_t*)(ws + OFF_WO1AT);
  ushort_t* WO1BT = (ushort_t*)(ws + OFF_WO1BT);
  ushort_t* WAST  = (ushort_t*)(ws + OFF_WAST);
  ushort_t* WSST  = (ushort_t*)(ws + OFF_WSST);
  ushort_t* ASG   = (ushort_t*)(ws + OFF_ASG);
  int*      BARp  = (int*)(ws + OFF_BAR);
  ushort_t* SKB   = (ushort_t*)(ws + OFF_SKB);

  const size_t t0 = (size_t)blockIdx.x * blockDim.x + threadIdx.x;
  const size_t st = (size_t)gridDim.x * blockDim.x;

  for (size_t i = t0; i < 512*512; i += st) {
    const int k = (int)(i >> 9), n = (int)(i & 511);
    const size_t d = (size_t)n * 512 + k;
    WSFT[d]  = f2bf(W_sf[i]);
    WAFT[d]  = f2bf(W_af[i]);
    WAST[d]  = f2bf(W_as[i]);
    WSST[d]  = f2bf(W_ss[i]);
    WO1AT[d] = f2bf(W_o1[i]);
    WO1BT[d] = f2bf(W_o1[i + (size_t)512*512]);
  }
  for (size_t i = t0; i < 512*512; i += st) ASG[i] = f2bf(ls_state[i & 511]);
  for (size_t i = t0; i < 512*512; i += st) {
    const size_t b = i >> 9, n = i & 511;
    SKB[(b * 199) * 512 + n] = f2bf(skill_state0[n]);
  }
  for (size_t i = t0; i < 512*199; i += st) d_out[i] = 0.f;
  for (size_t i = t0; i < 16*32; i += st) BARp[i] = 0;
}

// ---------------- tables: XA/XS/PROJ/GAPS/CAF ----------------
__global__ void rekt_tab(const float* __restrict__ se, const float* __restrict__ ae,
                         const float* __restrict__ te,
                         const float* __restrict__ W_sf, const float* __restrict__ b_sf,
                         const float* __restrict__ W_af, const float* __restrict__ b_af,
                         const float* __restrict__ W_ss, const float* __restrict__ b_ss,
                         const float* __restrict__ W_as, const float* __restrict__ b_as,
                         const float* __restrict__ W_o1, const float* __restrict__ b_o1,
                         char* __restrict__ ws) {
  __shared__ float ar[512];
  const int n = threadIdx.x;
  const int bid = blockIdx.x;
  const float* W; const float* bias; float* dst;
  if (bid < 600) {
    const int a = bid / 300, sk = bid % 300;
    ar[n] = se[(size_t)sk*512 + n] + ae[(size_t)a*512 + n];
    W = W_as + (size_t)512*512; bias = b_as; dst = (float*)(ws + OFF_XA) + (size_t)bid*512;
  } else if (bid < 1200) {
    const int r = bid - 600, a = r / 300, sk = r % 300;
    ar[n] = se[(size_t)sk*512 + n] + ae[(size_t)a*512 + n];
    W = W_ss + (size_t)512*512; bias = b_ss; dst = (float*)(ws + OFF_XS) + (size_t)r*512;
  } else if (bid < 1500) {
    const int r = bid - 1200;
    ar[n] = se[(size_t)r*512 + n];
    W = W_o1 + (size_t)1024*512; bias = b_o1; dst = (float*)(ws + OFF_PROJ) + (size_t)r*512;
  } else if (bid < 1700) {
    const int t = bid - 1500;
    ar[n] = te[(size_t)t*512 + n];
    W = W_sf + (size_t)512*512; bias = b_sf; dst = (float*)(ws + OFF_GAPS) + (size_t)t*512;
  } else {
    ar[n] = te[512 + n];
    W = W_af + (size_t)512*512; bias = b_af; dst = (float*)(ws + OFF_CAFV);
  }
  __syncthreads();
  float acc = bias[n];
  for (int k = 0; k < 512; ++k) acc = fmaf(ar[k], W[(size_t)k*512 + n], acc);
  dst[n] = acc;
}

// ---------------- per-step index precompute (pure function of static inputs) ----------------
__global__ void rekt_idx(const int* __restrict__ next_skill, const int* __restrict__ next_ans,
                         char* __restrict__ ws) {
  int* ISKR = (int*)(ws + OFF_ISKR);
  int* IGAP = (int*)(ws + OFF_IGAP);
  int* IXR  = (int*)(ws + OFF_IXR);
  int* ISK  = (int*)(ws + OFF_ISK);
  __shared__ int lt[300];
  const int b = blockIdx.x;
  for (int i = threadIdx.x; i < 300; i += blockDim.x) lt[i] = 0;
  __syncthreads();
  if (threadIdx.x == 0) {
    for (int s = 0; s < 199; ++s) {
      const int sk = next_skill[b * 199 + s];
      const int tl = lt[sk];
      ISKR[s * 512 + b] = b * 199 + tl;
      IGAP[s * 512 + b] = s - tl;
      IXR [s * 512 + b] = next_ans[b * 199 + s] * 300 + sk;
      ISK [s * 512 + b] = sk;
      lt[sk] = s;
    }
  }
}

// ---------------- fence-free split barrier (16 blocks/group), bounded spin ----------------
__device__ __forceinline__ void bar_sig(int* c) {
  __syncthreads();                    // drains vm stores before the signal
  if (threadIdx.x == 0)
    __hip_atomic_fetch_add(c, 1, __ATOMIC_RELAXED, __HIP_MEMORY_SCOPE_AGENT);
}
__device__ __forceinline__ void bar_wait(int* c, int target) {
  if (threadIdx.x == 0) {
    int guard = 0;
    while (__hip_atomic_load(c, __ATOMIC_RELAXED, __HIP_MEMORY_SCOPE_AGENT) < target) {
      __builtin_amdgcn_s_sleep(1);
      if (++guard > (1 << 22)) break;  // fail loud (bad absmax), never hang
    }
  }
  __syncthreads();
}

// ---------------- staging: 32 rows x 512 bf16 -> swizzled LDS tile (256 thr) ----------------
__device__ __forceinline__ void stage_g(short* T, const ushort_t* __restrict__ base,
                                        const int* rows, int tid) {
#pragma unroll
  for (int t = 0; t < 16; ++t) {
    const int i = t * 256 + tid;
    const int r = i >> 7, u = i & 127;
    const ull_t v = coh_ld8((const ull_t*)(base + (size_t)rows[r] * 512) + u);
    *reinterpret_cast<ull_t*>(T + r * 512 + ((((u >> 1) ^ (r & 7)) << 3) | ((u & 1) << 2))) = v;
  }
}
__device__ __forceinline__ void stage_l(short* T, const ushort_t* __restrict__ base, int tid) {
#pragma unroll
  for (int t = 0; t < 16; ++t) {
    const int i = t * 256 + tid;
    const int r = i >> 7, u = i & 127;
    const ull_t v = coh_ld8((const ull_t*)(base + (size_t)r * 512) + u);
    *reinterpret_cast<ull_t*>(T + r * 512 + ((((u >> 1) ^ (r & 7)) << 3) | ((u & 1) << 2))) = v;
  }
}

#define MFMA(a, b, c) __builtin_amdgcn_mfma_f32_16x16x32_bf16((a), (b), (c), 0, 0, 0)

// ---------------- main scan ----------------
// 256 blocks = 16 groups (32 batches) x 16 N-slices (32 cols).  256 thr = 4 waves:
// wave w: nt = w&1 (16-col tile), mh = w>>1 (16-row half).  Each wave owns its
// 16 cols through BOTH phases (la/ls in regs; all 4 GEMM chains; no cross-wave data).
__global__ __launch_bounds__(256, 2) void rekt_main(
    const float* __restrict__ w_o2,
    float* __restrict__ d_out, char* __restrict__ ws) {

  const ushort_t* WSFT  = (const ushort_t*)(ws + OFF_WSFT);
  const ushort_t* WAFT  = (const ushort_t*)(ws + OFF_WAFT);
  const ushort_t* WO1AT = (const ushort_t*)(ws + OFF_WO1AT);
  const ushort_t* WO1BT = (const ushort_t*)(ws + OFF_WO1BT);
  const ushort_t* WAST  = (const ushort_t*)(ws + OFF_WAST);
  const ushort_t* WSST  = (const ushort_t*)(ws + OFF_WSST);
  const float* GAPS = (const float*)(ws + OFF_GAPS);
  const float* CAFV = (const float*)(ws + OFF_CAFV);
  const float* XA   = (const float*)(ws + OFF_XA);
  const float* XS   = (const float*)(ws + OFF_XS);
  const float* PROJ = (const float*)(ws + OFF_PROJ);
  ushort_t* LAG = (ushort_t*)(ws + OFF_LAG);
  ushort_t* LSG = (ushort_t*)(ws + OFF_LSG);
  ushort_t* ASG = (ushort_t*)(ws + OFF_ASG);
  const int* ISKR = (const int*)(ws + OFF_ISKR);
  const int* IGAP = (const int*)(ws + OFF_IGAP);
  const int* IXR  = (const int*)(ws + OFF_IXR);
  const int* ISK  = (const int*)(ws + OFF_ISK);
  int*      BARp = (int*)(ws + OFF_BAR);
  ushort_t* SKB = (ushort_t*)(ws + OFF_SKB);

  __shared__ __align__(16) short Ta[32 * 512];
  __shared__ __align__(16) short Tb[32 * 512];
  __shared__ int sk_s[32], gap_s[32], xr_s[32], skrow_s[32];

  const int tid = threadIdx.x;
  const int lane = tid & 63, w = tid >> 6;
  const int cc = lane & 15, hi = lane >> 4;
  const int nt = w & 1, mh = w >> 1;
  const int g = blockIdx.x >> 4, sl = blockIdx.x & 15;
  const int b0 = g << 5;
  const int nc = sl * 32 + nt * 16 + cc;       // this lane's output column
  const int arow = mh * 16 + cc;               // A-fragment row in tile
  const int r0 = mh * 16 + hi * 4;             // acc row base (4 rows)
  const int aswz = (cc & 7) << 3;
  int* cA = BARp + g * 32;
  int* cB = cA + 1;

  const float cafv = CAFV[nc];
  const float wo2v = w_o2[nc];

  // B-operand column pointers ([n][k] layout, frag at col nc, k = j*32 + hi*8)
  const ushort_t* BSF = WSFT  + (size_t)nc * 512 + hi * 8;
  const ushort_t* BAF = WAFT  + (size_t)nc * 512 + hi * 8;
  const ushort_t* BHA = WO1AT + (size_t)nc * 512 + hi * 8;
  const ushort_t* BHB = WO1BT + (size_t)nc * 512 + hi * 8;
  const ushort_t* BNA = WAST  + (size_t)nc * 512 + hi * 8;
  const ushort_t* BNS = WSST  + (size_t)nc * 512 + hi * 8;

  for (int s = 0; s < 199; ++s) {
    // ---- prefetch phase-A weight frags (independent of the barrier) ----
    short8 FA[16], FG[16];
#pragma unroll
    for (int j = 0; j < 16; ++j) {
      FA[j] = *reinterpret_cast<const short8*>(BSF + j * 32);
      FG[j] = *reinterpret_cast<const short8*>(BAF + j * 32);
    }

    bar_wait(cB, 16 * s);                      // prev step's AS/SKB visible

    if (tid < 32) {
      const int o = s * 512 + b0 + tid;
      sk_s[tid]    = ISK[o];
      gap_s[tid]   = IGAP[o];
      xr_s[tid]    = IXR[o];
      skrow_s[tid] = ISKR[o];
    }
    __syncthreads();

    // ---- stage: Ta = SKg (gather), Tb = AS ----
    stage_g(Ta, SKB, skrow_s, tid);
    stage_l(Tb, ASG + (size_t)b0 * 512, tid);
    __syncthreads();

    // ---- phase A: F = SKg@Wsf, G = AS@Waf (both chains in every wave) ----
    f32x4 accF = {0.f, 0.f, 0.f, 0.f}, accG = {0.f, 0.f, 0.f, 0.f};
    {
      const short* a0 = Ta + arow * 512;
      const short* a1 = Tb + arow * 512;
#pragma unroll
      for (int j = 0; j < 16; ++j) {
        const int go = (((j * 4 + hi) << 3) ^ aswz);
        accF = MFMA(*reinterpret_cast<const short8*>(a0 + go), FA[j], accF);
        accG = MFMA(*reinterpret_cast<const short8*>(a1 + go), FG[j], accG);
      }
    }

    // ---- epilogue A: LS = SKg*sig(F+GAPS), LA = AS*sig(G+CAF); keep la/ls in regs ----
    f32x4 la, ls;
#pragma unroll
    for (int q = 0; q < 4; ++q) {
      const int r = r0 + q;
      const int si = r * 512 + (((nc >> 3) ^ (r & 7)) << 3) + (nc & 7);
      const float F = accF[q] + GAPS[(size_t)gap_s[r] * 512 + nc];
      const float lsv = bf2f((ushort_t)Ta[si]) * (1.f / (1.f + __expf(-F)));
      const float G = accG[q] + cafv;
      const float lav = bf2f((ushort_t)Tb[si]) * (1.f / (1.f + __expf(-G)));
      ls[q] = lsv; la[q] = lav;
      const uint_t ps = f2bf(lsv), pa = f2bf(lav);
      const uint_t os = (uint_t)__shfl_xor((int)ps, 1, 64);
      const uint_t oa = (uint_t)__shfl_xor((int)pa, 1, 64);
      if (!(cc & 1)) {
        coh_st4(LSG + (size_t)(b0 + r) * 512 + nc, ps | (os << 16));
        coh_st4(LAG + (size_t)(b0 + r) * 512 + nc, pa | (oa << 16));
      }
    }
    bar_sig(cA);

    // ---- prefetch H-chain weight frags while waiting ----
    short8 B1[16], B2[16];
#pragma unroll
    for (int j = 0; j < 16; ++j) {
      B1[j] = *reinterpret_cast<const short8*>(BHA + j * 32);
      B2[j] = *reinterpret_cast<const short8*>(BHB + j * 32);
    }
    bar_wait(cA, 16 * (s + 1));                // all slices' LA/LS visible

    // ---- stage: Ta = LA, Tb = LS ----
    stage_l(Ta, LAG + (size_t)b0 * 512, tid);
    stage_l(Tb, LSG + (size_t)b0 * 512, tid);
    __syncthreads();

    // ---- phase B: h = LA@Wo1A + LS@Wo1B; na = LA@Was; ns = LS@Wss ----
    f32x4 accH = {0.f, 0.f, 0.f, 0.f}, accN = accH, accS = accH;
    {
      const short* a0 = Ta + arow * 512;
      const short* a1 = Tb + arow * 512;
#pragma unroll
      for (int j = 0; j < 16; ++j) {
        const int go = (((j * 4 + hi) << 3) ^ aswz);
        const short8 aLA = *reinterpret_cast<const short8*>(a0 + go);
        const short8 aLS = *reinterpret_cast<const short8*>(a1 + go);
        accH = MFMA(aLA, B1[j], accH);
        accH = MFMA(aLS, B2[j], accH);
        accN = MFMA(aLA, *reinterpret_cast<const short8*>(BNA + j * 32), accN);
        accS = MFMA(aLS, *reinterpret_cast<const short8*>(BNS + j * 32), accS);
      }
    }

    // ---- epilogue B: P partial; AS' -> ASG; SK' -> SKB[s] ----
    float pv[4];
#pragma unroll
    for (int q = 0; q < 4; ++q) {
      const int r = r0 + q;
      const float h = fmaxf(accH[q] + PROJ[(size_t)sk_s[r] * 512 + nc], 0.f);
      pv[q] = h * wo2v;

      float x = accN[q] + XA[(size_t)xr_s[r] * 512 + nc];
      x = fminf(fmaxf(x, -12.f), 12.f);
      float e = __expf(2.f * x);
      const float nav = la[q] + (e - 1.f) / (e + 1.f);

      float y = accS[q] + XS[(size_t)xr_s[r] * 512 + nc];
      y = fminf(fmaxf(y, -12.f), 12.f);
      e = __expf(2.f * y);
      const float nsv = ls[q] + (e - 1.f) / (e + 1.f);

      const uint_t qa = f2bf(nav), qs = f2bf(nsv);
      const uint_t oa = (uint_t)__shfl_xor((int)qa, 1, 64);
      const uint_t os = (uint_t)__shfl_xor((int)qs, 1, 64);
      if (!(cc & 1)) {
        coh_st4(ASG + (size_t)(b0 + r) * 512 + nc, qa | (oa << 16));
        coh_st4(SKB + ((size_t)(b0 + r) * 199 + s) * 512 + nc, qs | (os << 16));
      }
    }
#pragma unroll
    for (int msk = 1; msk < 16; msk <<= 1) {
#pragma unroll
      for (int q = 0; q < 4; ++q) pv[q] += __shfl_xor(pv[q], msk, 64);
    }
    if (cc == 0) {
#pragma unroll
      for (int q = 0; q < 4; ++q) atomicAdd(&d_out[(size_t)(b0 + r0 + q) * 199 + s], pv[q]);
    }
    bar_sig(cB);
  }
}

// ---------------- tail: out = sigmoid(out + b_o2) ----------------
__global__ void rekt_out(float* __restrict__ d_out, const float* __restrict__ b_o2) {
  const int i = blockIdx.x * blockDim.x + threadIdx.x;
  if (i < 512 * 199) {
    const float v = d_out[i] + b_o2[0];
    d_out[i] = 1.f / (1.f + __expf(-v));
  }
}

extern "C" void kernel_launch(void* const* d_in, const int* in_sizes, int n_in,
                              void* d_out, int out_size, void* d_ws, size_t ws_size,
                              hipStream_t stream) {
  const int*   next_skill   = (const int*)d_in[4];
  const int*   next_ans     = (const int*)d_in[5];
  const float* skill_embed  = (const float*)d_in[6];
  const float* ans_embed    = (const float*)d_in[7];
  const float* time_embed   = (const float*)d_in[8];
  const float* ls_state     = (const float*)d_in[9];
  const float* skill_state0 = (const float*)d_in[10];
  const float* W_sf = (const float*)d_in[11];
  const float* b_sf = (const float*)d_in[12];
  const float* W_af = (const float*)d_in[13];
  const float* b_af = (const float*)d_in[14];
  const float* W_ss = (const float*)d_in[15];
  const float* b_ss = (const float*)d_in[16];
  const float* W_as = (const float*)d_in[17];
  const float* b_as = (const float*)d_in[18];
  const float* W_o1 = (const float*)d_in[19];
  const float* b_o1 = (const float*)d_in[20];
  const float* W_o2 = (const float*)d_in[21];
  const float* b_o2 = (const float*)d_in[22];
  float* out = (float*)d_out;
  char*  ws  = (char*)d_ws;

  if (ws_size < WS_NEED) return;

  rekt_prep<<<dim3(2048), dim3(256), 0, stream>>>(
      ls_state, skill_state0, W_sf, W_af, W_ss, W_as, W_o1, out, ws);
  rekt_tab<<<dim3(1701), dim3(512), 0, stream>>>(
      skill_embed, ans_embed, time_embed,
      W_sf, b_sf, W_af, b_af, W_ss, b_ss, W_as, b_as, W_o1, b_o1, ws);
  rekt_idx<<<dim3(512), dim3(64), 0, stream>>>(next_skill, next_ans, ws);

  rekt_main<<<dim3(256), dim3(256), 0, stream>>>(W_o2, out, ws);

  rekt_out<<<dim3((512 * 199 + 255) / 256), dim3(256), 0, stream>>>(out, b_o2);
}

// Round 10
// 4441.252 us; speedup vs baseline: 2.4367x; 2.4367x over previous
//
#include <hip/hip_runtime.h>

typedef unsigned short ushort_t;
typedef unsigned int uint_t;
typedef unsigned long long ull_t;
typedef __attribute__((ext_vector_type(8))) short short8;
typedef __attribute__((ext_vector_type(4))) float f32x4;
typedef __attribute__((ext_vector_type(4))) uint_t uint4v;

// ---------------- workspace layout (bytes) ----------------
constexpr size_t OFF_WSFT  = 0;                          // bf16 [512][512] (n,k): W_sf[k][n], k<512
constexpr size_t OFF_WAFT  = OFF_WSFT  + 512*512*2;      // bf16 [512][512]
constexpr size_t OFF_WO1AT = OFF_WAFT  + 512*512*2;      // bf16 [512][512]  W_o1 rows 0..511
constexpr size_t OFF_WO1BT = OFF_WO1AT + 512*512*2;      // bf16 [512][512]  W_o1 rows 512..1023
constexpr size_t OFF_WAST  = OFF_WO1BT + 512*512*2;      // bf16 [512][512]  W_as top
constexpr size_t OFF_WSST  = OFF_WAST  + 512*512*2;      // bf16 [512][512]  W_ss top
constexpr size_t OFF_GAPS  = OFF_WSST  + 512*512*2;      // f32 [200][512]  te@Wsf_bot + b_sf
constexpr size_t OFF_CAFV  = OFF_GAPS  + 200*512*4;      // f32 [512]       te1@Waf_bot + b_af
constexpr size_t OFF_XA    = OFF_CAFV  + 512*4;          // f32 [600][512]  X@Was_bot + b_as
constexpr size_t OFF_XS    = OFF_XA    + 600*512*4;      // f32 [600][512]  X@Wss_bot + b_ss
constexpr size_t OFF_PROJ  = OFF_XS    + 600*512*4;      // f32 [300][512]  se@Wo1c + b_o1
constexpr size_t OFF_LAG   = OFF_PROJ  + 300*512*4;      // bf16 [512][512] gated last_all
constexpr size_t OFF_LSG   = OFF_LAG   + 512*512*2;      // bf16 [512][512] gated last_sk
constexpr size_t OFF_ASG   = OFF_LSG   + 512*512*2;      // bf16 [512][512] all_state
constexpr size_t OFF_ISKR  = OFF_ASG   + 512*512*2;      // i32 [199][512] gather row
constexpr size_t OFF_IGAP  = OFF_ISKR  + 199*512*4;      // i32 [199][512] gap
constexpr size_t OFF_IXR   = OFF_IGAP  + 199*512*4;      // i32 [199][512] X row
constexpr size_t OFF_ISK   = OFF_IXR   + 199*512*4;      // i32 [199][512] skill
constexpr size_t OFF_BAR   = OFF_ISK   + 199*512*4;      // i32 [16 groups][2 phases][32] flags
constexpr size_t OFF_SKB   = OFF_BAR   + 16*64*4;        // bf16 [512][199][512] skill_buf
constexpr size_t WS_NEED   = OFF_SKB   + (size_t)512*199*512*2;

__device__ __forceinline__ ushort_t f2bf(float f) {
  union { float f; uint_t u; } v; v.f = f;
  uint_t u = v.u;
  return (ushort_t)((u + 0x7FFFu + ((u >> 16) & 1u)) >> 16);
}
__device__ __forceinline__ float bf2f(ushort_t h) {
  union { uint_t u; float f; } v; v.u = ((uint_t)h) << 16;
  return v.f;
}
__device__ __forceinline__ void coh_st4(void* p, uint_t v) {
  __hip_atomic_store((uint_t*)p, v, __ATOMIC_RELAXED, __HIP_MEMORY_SCOPE_AGENT);
}

// ---------------- prologue: transposes + state init ----------------
__global__ void rekt_prep(const float* __restrict__ ls_state, const float* __restrict__ skill_state0,
                          const float* __restrict__ W_sf, const float* __restrict__ W_af,
                          const float* __restrict__ W_ss, const float* __restrict__ W_as,
                          const float* __restrict__ W_o1,
                          float* __restrict__ d_out, char* __restrict__ ws) {
  ushort_t* WSFT  = (ushort_t*)(ws + OFF_WSFT);
  ushort_t* WAFT  = (ushort_t*)(ws + OFF_WAFT);
  ushort_t* WO1AT = (ushort_t*)(ws + OFF_WO1AT);
  ushort_t* WO1BT = (ushort_t*)(ws + OFF_WO1BT);
  ushort_t* WAST  = (ushort_t*)(ws + OFF_WAST);
  ushort_t* WSST  = (ushort_t*)(ws + OFF_WSST);
  ushort_t* ASG   = (ushort_t*)(ws + OFF_ASG);
  int*      BARp  = (int*)(ws + OFF_BAR);
  ushort_t* SKB   = (ushort_t*)(ws + OFF_SKB);

  const size_t t0 = (size_t)blockIdx.x * blockDim.x + threadIdx.x;
  const size_t st = (size_t)gridDim.x * blockDim.x;

  for (size_t i = t0; i < 512*512; i += st) {
    const int k = (int)(i >> 9), n = (int)(i & 511);
    const size_t d = (size_t)n * 512 + k;
    WSFT[d]  = f2bf(W_sf[i]);
    WAFT[d]  = f2bf(W_af[i]);
    WAST[d]  = f2bf(W_as[i]);
    WSST[d]  = f2bf(W_ss[i]);
    WO1AT[d] = f2bf(W_o1[i]);
    WO1BT[d] = f2bf(W_o1[i + (size_t)512*512]);
  }
  for (size_t i = t0; i < 512*512; i += st) ASG[i] = f2bf(ls_state[i & 511]);
  for (size_t i = t0; i < 512*512; i += st) {
    const size_t b = i >> 9, n = i & 511;
    SKB[(b * 199) * 512 + n] = f2bf(skill_state0[n]);
  }
  for (size_t i = t0; i < 512*199; i += st) d_out[i] = 0.f;
  for (size_t i = t0; i < 16*64; i += st) BARp[i] = 0;
}

// ---------------- tables: XA/XS/PROJ/GAPS/CAF ----------------
__global__ void rekt_tab(const float* __restrict__ se, const float* __restrict__ ae,
                         const float* __restrict__ te,
                         const float* __restrict__ W_sf, const float* __restrict__ b_sf,
                         const float* __restrict__ W_af, const float* __restrict__ b_af,
                         const float* __restrict__ W_ss, const float* __restrict__ b_ss,
                         const float* __restrict__ W_as, const float* __restrict__ b_as,
                         const float* __restrict__ W_o1, const float* __restrict__ b_o1,
                         char* __restrict__ ws) {
  __shared__ float ar[512];
  const int n = threadIdx.x;
  const int bid = blockIdx.x;
  const float* W; const float* bias; float* dst;
  if (bid < 600) {
    const int a = bid / 300, sk = bid % 300;
    ar[n] = se[(size_t)sk*512 + n] + ae[(size_t)a*512 + n];
    W = W_as + (size_t)512*512; bias = b_as; dst = (float*)(ws + OFF_XA) + (size_t)bid*512;
  } else if (bid < 1200) {
    const int r = bid - 600, a = r / 300, sk = r % 300;
    ar[n] = se[(size_t)sk*512 + n] + ae[(size_t)a*512 + n];
    W = W_ss + (size_t)512*512; bias = b_ss; dst = (float*)(ws + OFF_XS) + (size_t)r*512;
  } else if (bid < 1500) {
    const int r = bid - 1200;
    ar[n] = se[(size_t)r*512 + n];
    W = W_o1 + (size_t)1024*512; bias = b_o1; dst = (float*)(ws + OFF_PROJ) + (size_t)r*512;
  } else if (bid < 1700) {
    const int t = bid - 1500;
    ar[n] = te[(size_t)t*512 + n];
    W = W_sf + (size_t)512*512; bias = b_sf; dst = (float*)(ws + OFF_GAPS) + (size_t)t*512;
  } else {
    ar[n] = te[512 + n];
    W = W_af + (size_t)512*512; bias = b_af; dst = (float*)(ws + OFF_CAFV);
  }
  __syncthreads();
  float acc = bias[n];
  for (int k = 0; k < 512; ++k) acc = fmaf(ar[k], W[(size_t)k*512 + n], acc);
  dst[n] = acc;
}

// ---------------- per-step index precompute ----------------
__global__ void rekt_idx(const int* __restrict__ next_skill, const int* __restrict__ next_ans,
                         char* __restrict__ ws) {
  int* ISKR = (int*)(ws + OFF_ISKR);
  int* IGAP = (int*)(ws + OFF_IGAP);
  int* IXR  = (int*)(ws + OFF_IXR);
  int* ISK  = (int*)(ws + OFF_ISK);
  __shared__ int lt[300];
  const int b = blockIdx.x;
  for (int i = threadIdx.x; i < 300; i += blockDim.x) lt[i] = 0;
  __syncthreads();
  if (threadIdx.x == 0) {
    for (int s = 0; s < 199; ++s) {
      const int sk = next_skill[b * 199 + s];
      const int tl = lt[sk];
      ISKR[s * 512 + b] = b * 199 + tl;
      IGAP[s * 512 + b] = s - tl;
      IXR [s * 512 + b] = next_ans[b * 199 + s] * 300 + sk;
      ISK [s * 512 + b] = sk;
      lt[sk] = s;
    }
  }
}

// ---------------- flag barrier: parallel stores, 16-lane poll ----------------
__device__ __forceinline__ void bar_sig(int* flg, int sl, int val) {
  __syncthreads();                    // drains every wave's vm stores (vmcnt 0) first
  if (threadIdx.x == 0)
    __hip_atomic_store(flg + sl, val, __ATOMIC_RELAXED, __HIP_MEMORY_SCOPE_AGENT);
}
__device__ __forceinline__ void bar_wait(const int* flg, int val) {
  if (threadIdx.x < 16) {
    int guard = 0;
    while (__hip_atomic_load(flg + threadIdx.x, __ATOMIC_RELAXED, __HIP_MEMORY_SCOPE_AGENT) < val) {
      __builtin_amdgcn_s_sleep(1);
      if (++guard > (1 << 22)) break;  // fail loud (bad absmax), never hang
    }
  }
  __syncthreads();
}

// ---------------- staging: 2x (32 rows x 512 bf16) via 16B sc0sc1 loads, batched ----------------
template<bool GATHER>
__device__ __forceinline__ void stage2(short* Ta, short* Tb,
                                       const ushort_t* __restrict__ baseA, const int* rowsA,
                                       const ushort_t* __restrict__ baseB, int tid) {
  uint4v va[4], vb[4];
  int dst[4];
#pragma unroll
  for (int t = 0; t < 4; ++t) {
    const int i = t * 512 + tid;
    const int r = i >> 6, gi = i & 63;
    const size_t rowA = GATHER ? (size_t)rowsA[r] : (size_t)r;
    const ushort_t* pa = baseA + rowA * 512 + gi * 8;
    const ushort_t* pb = baseB + (size_t)r * 512 + gi * 8;
    asm volatile("global_load_dwordx4 %0, %1, off sc0 sc1" : "=v"(va[t]) : "v"(pa));
    asm volatile("global_load_dwordx4 %0, %1, off sc0 sc1" : "=v"(vb[t]) : "v"(pb));
    dst[t] = r * 512 + ((gi ^ (r & 7)) << 3);
  }
  asm volatile("s_waitcnt vmcnt(0)" ::: "memory");
  __builtin_amdgcn_sched_barrier(0);
#pragma unroll
  for (int t = 0; t < 4; ++t) {
    *reinterpret_cast<uint4v*>(Ta + dst[t]) = va[t];
    *reinterpret_cast<uint4v*>(Tb + dst[t]) = vb[t];
  }
}

#define MFMA(a, b, c) __builtin_amdgcn_mfma_f32_16x16x32_bf16((a), (b), (c), 0, 0, 0)

// ---------------- main scan ----------------
// 256 blocks = 16 groups (32 batches) x 16 N-slices (32 cols).  512 thr = 8 waves:
// wave w: m = w&1 (16-row half), nt = (w>>1)&1 (16-col tile), set = w>>2.
// LDS ~82.5KB pins 1 block/CU.
__global__ __launch_bounds__(512, 1) void rekt_main(
    const float* __restrict__ w_o2,
    float* __restrict__ d_out, char* __restrict__ ws) {

  const ushort_t* WSFT  = (const ushort_t*)(ws + OFF_WSFT);
  const ushort_t* WAFT  = (const ushort_t*)(ws + OFF_WAFT);
  const ushort_t* WO1AT = (const ushort_t*)(ws + OFF_WO1AT);
  const ushort_t* WO1BT = (const ushort_t*)(ws + OFF_WO1BT);
  const ushort_t* WAST  = (const ushort_t*)(ws + OFF_WAST);
  const ushort_t* WSST  = (const ushort_t*)(ws + OFF_WSST);
  const float* GAPS = (const float*)(ws + OFF_GAPS);
  const float* CAFV = (const float*)(ws + OFF_CAFV);
  const float* XA   = (const float*)(ws + OFF_XA);
  const float* XS   = (const float*)(ws + OFF_XS);
  const float* PROJ = (const float*)(ws + OFF_PROJ);
  ushort_t* LAG = (ushort_t*)(ws + OFF_LAG);
  ushort_t* LSG = (ushort_t*)(ws + OFF_LSG);
  ushort_t* ASG = (ushort_t*)(ws + OFF_ASG);
  const int* ISKR = (const int*)(ws + OFF_ISKR);
  const int* IGAP = (const int*)(ws + OFF_IGAP);
  const int* IXR  = (const int*)(ws + OFF_IXR);
  const int* ISK  = (const int*)(ws + OFF_ISK);
  int*      FLG = (int*)(ws + OFF_BAR);
  ushort_t* SKB = (ushort_t*)(ws + OFF_SKB);

  __shared__ __align__(16) short Ta[32 * 512];
  __shared__ __align__(16) short Tb[32 * 512];
  __shared__ float Hbuf[32 * 144];              // stride 144 pads LDS > 80KB (1 block/CU)
  __shared__ int sk_s[32], gap_s[32], xr_s[32], skrow_s[32];

  const int tid = threadIdx.x;
  const int lane = tid & 63, w = tid >> 6;
  const int cc = lane & 15, hi = lane >> 4;
  const int m = w & 1, nt = (w >> 1) & 1, setB = w >> 2;
  const int g = blockIdx.x >> 4, sl = blockIdx.x & 15;
  const int b0 = g << 5;
  const int nc = sl * 32 + nt * 16 + cc;       // this lane's output column
  const int ncl = nt * 16 + cc;                // block-local column
  const int arow = m * 16 + cc;                // A-fragment row in tile
  const int r0 = m * 16 + hi * 4;              // acc row base
  const int aswz = (cc & 7) << 3;
  int* flgA = FLG + g * 64;
  int* flgB = FLG + g * 64 + 32;

  const float cafv = CAFV[nc];
  const float wo2v = w_o2[nc];

  // set-split B-operand column pointers ([n][k] layout)
  const ushort_t* BA = (setB ? WAFT  : WSFT ) + (size_t)nc * 512 + hi * 8;
  const ushort_t* BH = (setB ? WO1BT : WO1AT) + (size_t)nc * 512 + hi * 8;
  const ushort_t* BU = (setB ? WSST  : WAST ) + (size_t)nc * 512 + hi * 8;

  for (int s = 0; s < 199; ++s) {
    // ---- index fill + phase-A frag prefetch: both independent of the barrier ----
    if (tid < 32) {
      const int o = s * 512 + b0 + tid;
      sk_s[tid]    = ISK[o];
      gap_s[tid]   = IGAP[o];
      xr_s[tid]    = IXR[o];
      skrow_s[tid] = ISKR[o];
    }
    short8 Bf[16];
#pragma unroll
    for (int j = 0; j < 16; ++j) Bf[j] = *reinterpret_cast<const short8*>(BA + j * 32);

    bar_wait(flgB, s);                         // prev step's AS/SKB visible (also publishes sk_s)

    // ---- stage: Ta = SKg (gather), Tb = AS ----
    stage2<true>(Ta, Tb, SKB, skrow_s, ASG + (size_t)b0 * 512, tid);
    __syncthreads();

    // ---- phase A: set0 fa = SKg@Wsf ; set1 ga = AS@Waf ----
    f32x4 accA = {0.f, 0.f, 0.f, 0.f};
    {
      const short* a0 = (setB ? Tb : Ta) + arow * 512;
#pragma unroll
      for (int j = 0; j < 16; ++j) {
        const short8 a = *reinterpret_cast<const short8*>(a0 + (((j * 4 + hi) << 3) ^ aswz));
        accA = MFMA(a, Bf[j], accA);
      }
    }

    // ---- epilogue A ----
    if (setB == 0) {                            // LS = SKg * sigmoid(fa + GAPS[gap])
#pragma unroll
      for (int q = 0; q < 4; ++q) {
        const int r = r0 + q;
        const float F = accA[q] + GAPS[(size_t)gap_s[r] * 512 + nc];
        const float sg = 1.f / (1.f + __expf(-F));
        const float skg = bf2f((ushort_t)Ta[r * 512 + (((nc >> 3) ^ (r & 7)) << 3) + (nc & 7)]);
        const uint_t pz = f2bf(skg * sg);
        const uint_t oz = (uint_t)__shfl_xor((int)pz, 1, 64);
        if (!(cc & 1)) coh_st4(LSG + (size_t)(b0 + r) * 512 + nc, pz | (oz << 16));
      }
    } else {                                    // LA = AS * sigmoid(ga + CAF)
#pragma unroll
      for (int q = 0; q < 4; ++q) {
        const int r = r0 + q;
        const float G = accA[q] + cafv;
        const float sg = 1.f / (1.f + __expf(-G));
        const float asv = bf2f((ushort_t)Tb[r * 512 + (((nc >> 3) ^ (r & 7)) << 3) + (nc & 7)]);
        const uint_t pz = f2bf(asv * sg);
        const uint_t oz = (uint_t)__shfl_xor((int)pz, 1, 64);
        if (!(cc & 1)) coh_st4(LAG + (size_t)(b0 + r) * 512 + nc, pz | (oz << 16));
      }
    }
    bar_sig(flgA, sl, s + 1);

    // ---- phase-B frag prefetch while others arrive ----
    short8 B1[16], B2[16];
#pragma unroll
    for (int j = 0; j < 16; ++j) {
      B1[j] = *reinterpret_cast<const short8*>(BH + j * 32);
      B2[j] = *reinterpret_cast<const short8*>(BU + j * 32);
    }
    bar_wait(flgA, s + 1);                     // all slices' LA/LS visible

    // ---- stage: Ta = LA, Tb = LS ----
    stage2<false>(Ta, Tb, LAG + (size_t)b0 * 512, nullptr, LSG + (size_t)b0 * 512, tid);
    __syncthreads();

    // ---- phase B: set0 {ha, na} from LA ; set1 {hb, ns} from LS ----
    f32x4 acc1 = {0.f, 0.f, 0.f, 0.f}, acc2 = {0.f, 0.f, 0.f, 0.f};
    {
      const short* a0 = (setB ? Tb : Ta) + arow * 512;
#pragma unroll
      for (int j = 0; j < 16; ++j) {
        const short8 a = *reinterpret_cast<const short8*>(a0 + (((j * 4 + hi) << 3) ^ aswz));
        acc1 = MFMA(a, B1[j], acc1);
        acc2 = MFMA(a, B2[j], acc2);
      }
    }

    // ---- epilogue B ----
    if (setB == 0) {                            // publish ha partial
#pragma unroll
      for (int q = 0; q < 4; ++q) Hbuf[(r0 + q) * 144 + ncl] = acc1[q];
    }
    __syncthreads();

    float pv[4];
    if (setB == 0) {                            // AS' = LA + tanh(na + XA[xr])
#pragma unroll
      for (int q = 0; q < 4; ++q) {
        const int r = r0 + q;
        float x = acc2[q] + XA[(size_t)xr_s[r] * 512 + nc];
        x = fminf(fmaxf(x, -12.f), 12.f);
        const float e = __expf(2.f * x);
        const float lav = bf2f((ushort_t)Ta[r * 512 + (((nc >> 3) ^ (r & 7)) << 3) + (nc & 7)]);
        const uint_t pz = f2bf(lav + (e - 1.f) / (e + 1.f));
        const uint_t oz = (uint_t)__shfl_xor((int)pz, 1, 64);
        if (!(cc & 1)) coh_st4(ASG + (size_t)(b0 + r) * 512 + nc, pz | (oz << 16));
      }
    } else {                                    // P partial (kept in regs) + SK' = LS + tanh(ns + XS)
#pragma unroll
      for (int q = 0; q < 4; ++q) {
        const int r = r0 + q;
        const float h = fmaxf(Hbuf[r * 144 + ncl] + acc1[q] + PROJ[(size_t)sk_s[r] * 512 + nc], 0.f);
        pv[q] = h * wo2v;

        float y = acc2[q] + XS[(size_t)xr_s[r] * 512 + nc];
        y = fminf(fmaxf(y, -12.f), 12.f);
        const float e = __expf(2.f * y);
        const float lsv = bf2f((ushort_t)Tb[r * 512 + (((nc >> 3) ^ (r & 7)) << 3) + (nc & 7)]);
        const uint_t pz = f2bf(lsv + (e - 1.f) / (e + 1.f));
        const uint_t oz = (uint_t)__shfl_xor((int)pz, 1, 64);
        if (!(cc & 1)) coh_st4(SKB + ((size_t)(b0 + r) * 199 + s) * 512 + nc, pz | (oz << 16));
      }
    }
    bar_sig(flgB, sl, s + 1);

    // ---- post-signal: P reduction + d_out atomic (off the critical path) ----
    if (setB == 1) {
#pragma unroll
      for (int msk = 1; msk < 16; msk <<= 1) {
#pragma unroll
        for (int q = 0; q < 4; ++q) pv[q] += __shfl_xor(pv[q], msk, 64);
      }
      if (cc == 0) {
#pragma unroll
        for (int q = 0; q < 4; ++q) atomicAdd(&d_out[(size_t)(b0 + r0 + q) * 199 + s], pv[q]);
      }
    }
  }
}

// ---------------- tail: out = sigmoid(out + b_o2) ----------------
__global__ void rekt_out(float* __restrict__ d_out, const float* __restrict__ b_o2) {
  const int i = blockIdx.x * blockDim.x + threadIdx.x;
  if (i < 512 * 199) {
    const float v = d_out[i] + b_o2[0];
    d_out[i] = 1.f / (1.f + __expf(-v));
  }
}

extern "C" void kernel_launch(void* const* d_in, const int* in_sizes, int n_in,
                              void* d_out, int out_size, void* d_ws, size_t ws_size,
                              hipStream_t stream) {
  const int*   next_skill   = (const int*)d_in[4];
  const int*   next_ans     = (const int*)d_in[5];
  const float* skill_embed  = (const float*)d_in[6];
  const float* ans_embed    = (const float*)d_in[7];
  const float* time_embed   = (const float*)d_in[8];
  const float* ls_state     = (const float*)d_in[9];
  const float* skill_state0 = (const float*)d_in[10];
  const float* W_sf = (const float*)d_in[11];
  const float* b_sf = (const float*)d_in[12];
  const float* W_af = (const float*)d_in[13];
  const float* b_af = (const float*)d_in[14];
  const float* W_ss = (const float*)d_in[15];
  const float* b_ss = (const float*)d_in[16];
  const float* W_as = (const float*)d_in[17];
  const float* b_as = (const float*)d_in[18];
  const float* W_o1 = (const float*)d_in[19];
  const float* b_o1 = (const float*)d_in[20];
  const float* W_o2 = (const float*)d_in[21];
  const float* b_o2 = (const float*)d_in[22];
  float* out = (float*)d_out;
  char*  ws  = (char*)d_ws;

  if (ws_size < WS_NEED) return;

  rekt_prep<<<dim3(2048), dim3(256), 0, stream>>>(
      ls_state, skill_state0, W_sf, W_af, W_ss, W_as, W_o1, out, ws);
  rekt_tab<<<dim3(1701), dim3(512), 0, stream>>>(
      skill_embed, ans_embed, time_embed,
      W_sf, b_sf, W_af, b_af, W_ss, b_ss, W_as, b_as, W_o1, b_o1, ws);
  rekt_idx<<<dim3(512), dim3(64), 0, stream>>>(next_skill, next_ans, ws);

  rekt_main<<<dim3(256), dim3(512), 0, stream>>>(W_o2, out, ws);

  rekt_out<<<dim3((512 * 199 + 255) / 256), dim3(256), 0, stream>>>(out, b_o2);
}